// Round 1
// baseline (226.108 us; speedup 1.0000x reference)
//
#include <hip/hip_runtime.h>
#include <math.h>

#define NB 2
#define NC 256
#define NS 4096
#define NG 32
#define CPG 8
#define NH 4
#define DK 64
#define NQKV 768

typedef __attribute__((ext_vector_type(8))) short short8;
typedef __attribute__((ext_vector_type(4))) float f32x4;

__device__ __forceinline__ short f2bf(float f){
  union { float f; unsigned u; } v; v.f = f;
  unsigned r = v.u + 0x7fffu + ((v.u >> 16) & 1u);
  return (short)(r >> 16);
}

// ---- K1: group-norm stats: one block per (b, group); group block is contiguous 32768 floats ----
__global__ __launch_bounds__(256) void k_gnstats(const float* __restrict__ x,
                                                 float* __restrict__ mean,
                                                 float* __restrict__ rstd){
  int bg = blockIdx.x;                       // b*32 + g
  const float* base = x + (size_t)bg * (CPG*NS);
  float s = 0.f, ss = 0.f;
  for (int i = threadIdx.x; i < CPG*NS; i += 256){
    float v = base[i]; s += v; ss += v*v;
  }
  for (int o = 32; o > 0; o >>= 1){ s += __shfl_down(s, o); ss += __shfl_down(ss, o); }
  __shared__ float red[8];
  int w = threadIdx.x >> 6;
  if ((threadIdx.x & 63) == 0){ red[w] = s; red[4+w] = ss; }
  __syncthreads();
  if (threadIdx.x == 0){
    float S  = red[0]+red[1]+red[2]+red[3];
    float SS = red[4]+red[5]+red[6]+red[7];
    const float inv = 1.f/(float)(CPG*NS);
    float m = S*inv; float var = SS*inv - m*m;
    mean[bg] = m; rstd[bg] = rsqrtf(var + 1e-5f);
  }
}

// ---- K2: normalize + transpose [B,C,S] -> h[B,S,C] bf16 (LDS tile, pad +2 shorts) ----
__global__ __launch_bounds__(256) void k_gnapply(const float* __restrict__ x,
                                                 const float* __restrict__ gw,
                                                 const float* __restrict__ gb,
                                                 const float* __restrict__ mean,
                                                 const float* __restrict__ rstd,
                                                 short* __restrict__ h){
  __shared__ short tile[64][258];
  int b  = blockIdx.x >> 6;
  int s0 = (blockIdx.x & 63) << 6;
  int sl = threadIdx.x & 63;
  int c0 = threadIdx.x >> 6;
  for (int ci = 0; ci < NC; ci += 4){
    int c = ci + c0;
    int sg = (b << 5) + (c >> 3);
    float v  = x[((size_t)b*NC + c)*NS + s0 + sl];
    float hn = (v - mean[sg]) * rstd[sg] * gw[c] + gb[c];
    tile[sl][c] = f2bf(hn);
  }
  __syncthreads();
  for (int it = 0; it < 32; ++it){
    int idx = it*256 + threadIdx.x;
    int row = idx >> 7, col = (idx & 127) << 1;
    unsigned p = ((unsigned)(unsigned short)tile[row][col]) |
                 (((unsigned)(unsigned short)tile[row][col+1]) << 16);
    *(unsigned*)&h[((size_t)b*NS + s0 + row)*NC + col] = p;
  }
}

// ---- K3: weights f32 -> bf16 ----
__global__ __launch_bounds__(256) void k_cvtw(const float* __restrict__ pw,
                                              const float* __restrict__ ow,
                                              short* __restrict__ pwb,
                                              short* __restrict__ owb){
  int i = blockIdx.x*256 + threadIdx.x;
  if (i < NQKV*NC) pwb[i] = f2bf(pw[i]);
  if (i < NC*NC)   owb[i] = f2bf(ow[i]);
}

// ---- K4: QKV GEMM: [8192,256] x [768,256]^T, scatter epilogue to q/k/vT ----
__global__ __launch_bounds__(256) void k_qkv(const short* __restrict__ h,
                                             const short* __restrict__ wb,
                                             const float* __restrict__ pb,
                                             short* __restrict__ qo,
                                             short* __restrict__ ko,
                                             short* __restrict__ vto){
  __shared__ short As[128][40];
  __shared__ short Bs[128][40];
  int m0 = blockIdx.x << 7;
  int n0 = blockIdx.y << 7;
  int tid = threadIdx.x;
  int lane = tid & 63, wid = tid >> 6;
  int wm = (wid >> 1) << 6, wn = (wid & 1) << 6;
  int l15 = lane & 15, lg = lane >> 4;
  const f32x4 fz = {0.f,0.f,0.f,0.f};
  f32x4 acc[4][4];
  for (int i=0;i<4;i++) for(int j=0;j<4;j++) acc[i][j] = fz;
  for (int k0 = 0; k0 < NC; k0 += 32){
    __syncthreads();
    for (int it = 0; it < 2; ++it){
      int c = it*256 + tid;
      int r = c >> 2, kk8 = (c & 3) << 3;
      *(short8*)&As[r][kk8] = *(const short8*)&h [((size_t)(m0 + r))*NC + k0 + kk8];
      *(short8*)&Bs[r][kk8] = *(const short8*)&wb[((size_t)(n0 + r))*NC + k0 + kk8];
    }
    __syncthreads();
    short8 a[4], b[4];
    for (int mf=0; mf<4; ++mf) a[mf] = *(const short8*)&As[wm + mf*16 + l15][lg*8];
    for (int nf=0; nf<4; ++nf) b[nf] = *(const short8*)&Bs[wn + nf*16 + l15][lg*8];
    for (int mf=0; mf<4; ++mf)
      for (int nf=0; nf<4; ++nf)
        acc[mf][nf] = __builtin_amdgcn_mfma_f32_16x16x32_bf16(a[mf], b[nf], acc[mf][nf], 0,0,0);
  }
  for (int mf=0; mf<4; ++mf)
    for (int nf=0; nf<4; ++nf)
      for (int r=0; r<4; ++r){
        int m = m0 + wm + mf*16 + lg*4 + r;
        int o = n0 + wn + nf*16 + l15;
        float val = acc[mf][nf][r] + pb[o];
        int b_ = m >> 12, s = m & 4095;
        int hh = o / 192, rem = o - hh*192;
        int t = rem >> 6, d = rem & 63;
        size_t bh = (size_t)(b_*NH + hh);
        short bv = f2bf(val);
        if (t == 0)      qo [(bh*NS + s)*DK + d] = bv;
        else if (t == 1) ko [(bh*NS + s)*DK + d] = bv;
        else             vto[(bh*DK + d)*NS + s] = bv;
      }
}

// ---- K5: flash attention: 1 block = (bh, 64 q-rows), KV tiles of 64 ----
__global__ __launch_bounds__(256) void k_attn(const short* __restrict__ q,
                                              const short* __restrict__ k,
                                              const short* __restrict__ vt,
                                              short* __restrict__ ao){
  __shared__ short Ks[64][72];
  __shared__ short Vs[64][72];      // Vs[d][kv]
  __shared__ short Ps[4][16][72];   // per-wave P tile [q(16)][kv(64)]
  int blk = blockIdx.x;
  int q0 = (blk & 63) << 6;
  int bh = blk >> 6;
  const short* Qb = q  + (size_t)bh*NS*DK;
  const short* Kb = k  + (size_t)bh*NS*DK;
  const short* Vb = vt + (size_t)bh*DK*NS;
  int tid = threadIdx.x, lane = tid & 63, wid = tid >> 6;
  int l15 = lane & 15, lg = lane >> 4;
  short8 aq[2];
  {
    const short* qrow = Qb + (size_t)(q0 + wid*16 + l15)*DK + lg*8;
    aq[0] = *(const short8*)qrow;
    aq[1] = *(const short8*)(qrow + 32);
  }
  const f32x4 fz = {0.f,0.f,0.f,0.f};
  f32x4 acc[4];
  for (int i=0;i<4;i++) acc[i] = fz;
  float mrun[4], lrun[4];
  for (int r=0;r<4;r++){ mrun[r] = -1e30f; lrun[r] = 0.f; }
  for (int kv0 = 0; kv0 < NS; kv0 += 64){
    __syncthreads();
    for (int it = 0; it < 2; ++it){
      int c = it*256 + tid;
      int r = c >> 3, col = (c & 7) << 3;
      *(short8*)&Ks[r][col] = *(const short8*)&Kb[(size_t)(kv0 + r)*DK + col];
      *(short8*)&Vs[r][col] = *(const short8*)&Vb[(size_t)r*NS + kv0 + col];
    }
    __syncthreads();
    f32x4 sa[4];
    for (int nf=0;nf<4;nf++) sa[nf] = fz;
    for (int nf=0;nf<4;nf++)
      for (int kk=0;kk<2;kk++){
        short8 bk = *(const short8*)&Ks[nf*16 + l15][kk*32 + lg*8];
        sa[nf] = __builtin_amdgcn_mfma_f32_16x16x32_bf16(aq[kk], bk, sa[nf], 0,0,0);
      }
    for (int r=0;r<4;r++){
      float sv[4];
      float mx = -1e30f;
      for (int nf=0;nf<4;nf++){ sv[nf] = sa[nf][r]*0.125f; mx = fmaxf(mx, sv[nf]); }
      for (int off=1; off<16; off<<=1) mx = fmaxf(mx, __shfl_xor(mx, off));
      float mnew = fmaxf(mrun[r], mx);
      float corr = __expf(mrun[r] - mnew);
      mrun[r] = mnew;
      float psum = 0.f;
      for (int nf=0;nf<4;nf++){
        float p = __expf(sv[nf] - mnew);
        psum += p;
        Ps[wid][lg*4 + r][nf*16 + l15] = f2bf(p);
      }
      for (int off=1; off<16; off<<=1) psum += __shfl_xor(psum, off);
      lrun[r] = lrun[r]*corr + psum;
      for (int nf=0;nf<4;nf++) acc[nf][r] *= corr;
    }
    __syncthreads();   // fence: P writes visible/ordered before PV fragment reads
    for (int nf=0;nf<4;nf++)
      for (int kk=0;kk<2;kk++){
        short8 ap = *(const short8*)&Ps[wid][l15][kk*32 + lg*8];
        short8 bv = *(const short8*)&Vs[nf*16 + l15][kk*32 + lg*8];
        acc[nf] = __builtin_amdgcn_mfma_f32_16x16x32_bf16(ap, bv, acc[nf], 0,0,0);
      }
  }
  int b_ = bh >> 2, hh = bh & 3;
  for (int nf=0;nf<4;nf++)
    for (int r=0;r<4;r++){
      int s = q0 + wid*16 + lg*4 + r;
      int d = nf*16 + l15;
      float val = acc[nf][r] / lrun[r];
      ao[((size_t)b_*NS + s)*NC + hh*DK + d] = f2bf(val);
    }
}

// ---- K6: out GEMM + bias + residual ----
__global__ __launch_bounds__(256) void k_out(const short* __restrict__ aoin,
                                             const short* __restrict__ wb,
                                             const float* __restrict__ ob,
                                             const float* __restrict__ x,
                                             float* __restrict__ out){
  __shared__ short As[128][40];
  __shared__ short Bs[128][40];
  int m0 = blockIdx.x << 7;
  int n0 = blockIdx.y << 7;
  int tid = threadIdx.x;
  int lane = tid & 63, wid = tid >> 6;
  int wm = (wid >> 1) << 6, wn = (wid & 1) << 6;
  int l15 = lane & 15, lg = lane >> 4;
  const f32x4 fz = {0.f,0.f,0.f,0.f};
  f32x4 acc[4][4];
  for (int i=0;i<4;i++) for(int j=0;j<4;j++) acc[i][j] = fz;
  for (int k0 = 0; k0 < NC; k0 += 32){
    __syncthreads();
    for (int it = 0; it < 2; ++it){
      int c = it*256 + tid;
      int r = c >> 2, kk8 = (c & 3) << 3;
      *(short8*)&As[r][kk8] = *(const short8*)&aoin[((size_t)(m0 + r))*NC + k0 + kk8];
      *(short8*)&Bs[r][kk8] = *(const short8*)&wb  [((size_t)(n0 + r))*NC + k0 + kk8];
    }
    __syncthreads();
    short8 a[4], b[4];
    for (int mf=0; mf<4; ++mf) a[mf] = *(const short8*)&As[wm + mf*16 + l15][lg*8];
    for (int nf=0; nf<4; ++nf) b[nf] = *(const short8*)&Bs[wn + nf*16 + l15][lg*8];
    for (int mf=0; mf<4; ++mf)
      for (int nf=0; nf<4; ++nf)
        acc[mf][nf] = __builtin_amdgcn_mfma_f32_16x16x32_bf16(a[mf], b[nf], acc[mf][nf], 0,0,0);
  }
  for (int mf=0; mf<4; ++mf)
    for (int nf=0; nf<4; ++nf)
      for (int r=0; r<4; ++r){
        int m = m0 + wm + mf*16 + lg*4 + r;
        int o = n0 + wn + nf*16 + l15;
        int b_ = m >> 12, s = m & 4095;
        size_t idx = ((size_t)b_*NC + o)*NS + s;
        out[idx] = acc[mf][nf][r] + ob[o] + x[idx];
      }
}

extern "C" void kernel_launch(void* const* d_in, const int* in_sizes, int n_in,
                              void* d_out, int out_size, void* d_ws, size_t ws_size,
                              hipStream_t stream){
  const float* x   = (const float*)d_in[0];
  const float* gnw = (const float*)d_in[1];
  const float* gnb = (const float*)d_in[2];
  const float* pw  = (const float*)d_in[3];
  const float* pb  = (const float*)d_in[4];
  const float* ow  = (const float*)d_in[5];
  const float* ob  = (const float*)d_in[6];
  float* out = (float*)d_out;

  char* ws = (char*)d_ws;
  float* mean = (float*)ws;
  float* rstd = mean + 64;
  short* wqkv = (short*)(ws + 512);
  short* wout = wqkv + NQKV*NC;
  short* h    = wout + NC*NC;
  short* qb   = h   + (size_t)NB*NS*NC;
  short* kb   = qb  + (size_t)NB*NH*NS*DK;
  short* vtb  = kb  + (size_t)NB*NH*NS*DK;
  short* ao   = vtb + (size_t)NB*NH*NS*DK;

  k_gnstats<<<64, 256, 0, stream>>>(x, mean, rstd);
  k_cvtw<<<768, 256, 0, stream>>>(pw, ow, wqkv, wout);
  k_gnapply<<<128, 256, 0, stream>>>(x, gnw, gnb, mean, rstd, h);
  k_qkv<<<dim3(64, 6), 256, 0, stream>>>(h, wqkv, pb, qb, kb, vtb);
  k_attn<<<512, 256, 0, stream>>>(qb, kb, vtb, ao);
  k_out<<<dim3(64, 2), 256, 0, stream>>>(ao, wout, ob, x, out);
}